// Round 17
// baseline (304.384 us; speedup 1.0000x reference)
//
#include <hip/hip_runtime.h>
#include <math.h>

#define N_NODES   100000
#define N_EDGES   1600000
#define E_TOT     (N_EDGES + N_NODES)
#define N_FEAT    512
#define HEADS     8
#define F_HEAD    8
#define HIDDEN    64
#define N_CLASSES 40

#define BSHIFT    9
#define NBUCK     196                      // ceil(N_NODES / 512)
#define SC_NBLK   512
#define SC_CHUNK  ((E_TOT + SC_NBLK - 1) / SC_NBLK)   // 3321

#define CT        5                        // B ct-tiles: 4 (W1) + 1 (Wsrc|Wdst)

typedef __attribute__((ext_vector_type(8))) short short8_t;
typedef __attribute__((ext_vector_type(4))) float f32x4;
typedef _Float16 half_t;
typedef __attribute__((ext_vector_type(8))) _Float16 h16x8;

// split fp32 -> bf16 hi + bf16 lo (both RNE)
__device__ inline void f2bf2(float x, unsigned short& h, unsigned short& l) {
  union { float f; unsigned u; } a; a.f = x;
  unsigned rh = a.u + 0x7FFFu + ((a.u >> 16) & 1u);
  unsigned short hv = (unsigned short)(rh >> 16);
  union { unsigned u; float f; } hf; hf.u = ((unsigned)hv) << 16;
  union { float f; unsigned u; } b; b.f = x - hf.f;
  unsigned rl = b.u + 0x7FFFu + ((b.u >> 16) & 1u);
  h = hv;
  l = (unsigned short)(rl >> 16);
}

__device__ inline void cvt8(const float4& v0, const float4& v1, short8_t& hi, short8_t& lo) {
  float v[8] = {v0.x, v0.y, v0.z, v0.w, v1.x, v1.y, v1.z, v1.w};
#pragma unroll
  for (int e = 0; e < 8; ++e) {
    unsigned short hh, ll;
    f2bf2(v[e], hh, ll);
    hi[e] = (short)hh;
    lo[e] = (short)ll;
  }
}

// ============================ CSR build: two-level counting sort ============================

__global__ __launch_bounds__(256) void k_bhist(const int* __restrict__ ei,
                                               int* __restrict__ ghT) {
  __shared__ int h[NBUCK];
  int b = blockIdx.x, t = threadIdx.x;
  for (int i = t; i < NBUCK; i += 256) h[i] = 0;
  __syncthreads();
  int e0 = b * SC_CHUNK;
  int e1 = e0 + SC_CHUNK; if (e1 > E_TOT) e1 = E_TOT;
  for (int e = e0 + t; e < e1; e += 256) {
    int dst = (e < N_EDGES) ? ei[N_EDGES + e] : (e - N_EDGES);
    atomicAdd(&h[dst >> BSHIFT], 1);
  }
  __syncthreads();
  for (int i = t; i < NBUCK; i += 256) ghT[i * SC_NBLK + b] = h[i];
}

// per-bucket: exclusive prefix over 512 blocks (2 elems/thread) + bucket total
__global__ __launch_bounds__(256) void k_scan1(int* __restrict__ ghT,
                                               int* __restrict__ btot) {
  __shared__ int red[256];
  int k = blockIdx.x, t = threadIdx.x;
  int a = ghT[k * SC_NBLK + 2 * t];
  int b = ghT[k * SC_NBLK + 2 * t + 1];
  int s = a + b;
  red[t] = s;
  __syncthreads();
  for (int off = 1; off < 256; off <<= 1) {
    int add = (t >= off) ? red[t - off] : 0;
    __syncthreads();
    red[t] += add;
    __syncthreads();
  }
  int excl = red[t] - s;
  ghT[k * SC_NBLK + 2 * t]     = excl;
  ghT[k * SC_NBLK + 2 * t + 1] = excl + a;
  if (t == 255) btot[k] = red[255];
}

__global__ __launch_bounds__(256) void k_scan2(const int* __restrict__ btot,
                                               int* __restrict__ bbase) {
  __shared__ int red[256];
  int t = threadIdx.x;
  int v = (t < NBUCK) ? btot[t] : 0;
  red[t] = v;
  __syncthreads();
  for (int off = 1; off < 256; off <<= 1) {
    int add = (t >= off) ? red[t - off] : 0;
    __syncthreads();
    red[t] += add;
    __syncthreads();
  }
  if (t < NBUCK) bbase[t] = red[t] - v;
  if (t == NBUCK - 1) bbase[NBUCK] = red[t];
}

__global__ __launch_bounds__(256) void k_bscatter(const int* __restrict__ ei,
                                                  const int* __restrict__ ghT,
                                                  const int* __restrict__ bbase,
                                                  unsigned* __restrict__ ebuf) {
  __shared__ int offs[256];
  __shared__ int cnt[256];
  int b = blockIdx.x, t = threadIdx.x;
  offs[t] = (t < NBUCK) ? (ghT[t * SC_NBLK + b] + bbase[t]) : 0;
  cnt[t] = 0;
  __syncthreads();
  int e0 = b * SC_CHUNK;
  int e1 = e0 + SC_CHUNK; if (e1 > E_TOT) e1 = E_TOT;
  for (int e = e0 + t; e < e1; e += 256) {
    int src, dst;
    if (e < N_EDGES) { src = ei[e]; dst = ei[N_EDGES + e]; }
    else             { src = e - N_EDGES; dst = src; }
    int k = dst >> BSHIFT;
    int r = atomicAdd(&cnt[k], 1);
    ebuf[offs[k] + r] = (unsigned)src | ((unsigned)(dst & 511) << 17);
  }
}

__global__ __launch_bounds__(256) void k_fine(const unsigned* __restrict__ ebuf,
                                              const int* __restrict__ bbase,
                                              int* __restrict__ rowp,
                                              int* __restrict__ ssrc) {
  __shared__ int cnt[512];
  __shared__ int red[256];
  __shared__ int cur[512];
  int k = blockIdx.x, t = threadIdx.x;
  int base = bbase[k], end = bbase[k + 1];
  cnt[t] = 0; cnt[t + 256] = 0;
  __syncthreads();
  for (int i = base + t; i < end; i += 256) atomicAdd(&cnt[ebuf[i] >> 17], 1);
  __syncthreads();
  int c0 = cnt[2 * t], c1 = cnt[2 * t + 1];
  int s = c0 + c1;
  red[t] = s;
  __syncthreads();
  for (int off = 1; off < 256; off <<= 1) {
    int add = (t >= off) ? red[t - off] : 0;
    __syncthreads();
    red[t] += add;
    __syncthreads();
  }
  int excl = red[t] - s;
  int p0 = base + excl;
  int p1 = p0 + c0;
  cur[2 * t] = p0; cur[2 * t + 1] = p1;
  int node = (k << BSHIFT) + 2 * t;
  if (node < N_NODES)     rowp[node]     = p0;
  if (node + 1 < N_NODES) rowp[node + 1] = p1;
  if (k == NBUCK - 1 && t == 0) rowp[N_NODES] = E_TOT;
  __syncthreads();
  for (int i = base + t; i < end; i += 256) {
    unsigned p = ebuf[i];
    int pos = atomicAdd(&cur[p >> 17], 1);
    ssrc[pos] = (int)(p & 0x1FFFFu);
  }
}

// ============================ W1/Wsrc/Wdst -> fragment-ordered bf16 hi/lo (fused) ============

__global__ void k_wprep(const float* __restrict__ W1, const float* __restrict__ att_src1,
                        const float* __restrict__ att_dst1, short* __restrict__ w1fh,
                        short* __restrict__ w1fl) {
  int idx = blockIdx.x * blockDim.x + threadIdx.x;
  if (idx < N_FEAT * HIDDEN) {
    int e    = idx & 7;
    int lane = (idx >> 3) & 63;
    int ct   = (idx >> 9) & 3;
    int ks   = idx >> 11;
    int col = ct * 16 + (lane & 15);
    int k   = ks * 32 + (lane >> 4) * 8 + e;
    unsigned short h, l;
    f2bf2(W1[k * HIDDEN + col], h, l);
    int didx = ((ks * CT + ct) * 64 + lane) * 8 + e;
    w1fh[didx] = (short)h;
    w1fl[didx] = (short)l;
  } else if (idx < N_FEAT * HIDDEN + N_FEAT * 16) {
    int i2 = idx - N_FEAT * HIDDEN;
    int c = i2 & 15;
    int k = i2 >> 4;
    int cc = c & 7;
    const float* att = (c < 8) ? att_src1 : att_dst1;
    float v = 0.f;
#pragma unroll
    for (int f = 0; f < 8; ++f) v = fmaf(W1[k * HIDDEN + cc * 8 + f], att[cc * 8 + f], v);
    unsigned short h, l;
    f2bf2(v, h, l);
    int lane = ((k >> 3) & 3) * 16 + c;
    int ks = k >> 5, e = k & 7;
    int didx = ((ks * CT + 4) * 64 + lane) * 8 + e;
    w1fh[didx] = (short)h;
    w1fl[didx] = (short)l;
  }
}

// ============================ Layer 1 GEMM: [h1 | a_src1 | a_dst1] = x @ [W1|Wsrc|Wdst] ============

__global__ __launch_bounds__(256) void k_gemm1(const float* __restrict__ x,
                                               const short* __restrict__ w1fh,
                                               const short* __restrict__ w1fl,
                                               half_t* __restrict__ h1h,
                                               half_t* __restrict__ a_srch,
                                               float* __restrict__ a_dst1) {
  int t = threadIdx.x;
  int w = t >> 6, l = t & 63;
  int n0 = blockIdx.x * 128 + w * 32;
  int r0 = l & 15;
  int kq8 = (l >> 4) * 8;
  const float* pA = x + (size_t)(n0 + r0) * N_FEAT + kq8;
  const float* pB = x + (size_t)(n0 + 16 + r0) * N_FEAT + kq8;
  bool vA = (n0 + r0) < N_NODES;
  bool vB = (n0 + 16 + r0) < N_NODES;

  f32x4 acc[2][CT];
#pragma unroll
  for (int i = 0; i < 2; ++i)
#pragma unroll
    for (int j = 0; j < CT; ++j) acc[i][j] = (f32x4){0.f, 0.f, 0.f, 0.f};

#pragma unroll 2
  for (int gks = 0; gks < 16; ++gks) {
    int boff = gks * (CT * 512) + l * 8;
    short8_t bh[CT], bl[CT];
#pragma unroll
    for (int ct = 0; ct < CT; ++ct) {
      bh[ct] = *(const short8_t*)(w1fh + boff + ct * 512);
      bl[ct] = *(const short8_t*)(w1fl + boff + ct * 512);
    }
    float4 a0 = make_float4(0.f, 0.f, 0.f, 0.f), a1 = a0, c0 = a0, c1 = a0;
    if (vA) {
      const float4* p = (const float4*)(pA + gks * 32);
      a0 = p[0]; a1 = p[1];
    }
    if (vB) {
      const float4* p = (const float4*)(pB + gks * 32);
      c0 = p[0]; c1 = p[1];
    }
    short8_t ahA, alA, ahB, alB;
    cvt8(a0, a1, ahA, alA);
    cvt8(c0, c1, ahB, alB);
#pragma unroll
    for (int ct = 0; ct < CT; ++ct) {
      acc[0][ct] = __builtin_amdgcn_mfma_f32_16x16x32_bf16(ahA, bh[ct], acc[0][ct], 0, 0, 0);
      acc[0][ct] = __builtin_amdgcn_mfma_f32_16x16x32_bf16(ahA, bl[ct], acc[0][ct], 0, 0, 0);
      acc[0][ct] = __builtin_amdgcn_mfma_f32_16x16x32_bf16(alA, bh[ct], acc[0][ct], 0, 0, 0);
      acc[1][ct] = __builtin_amdgcn_mfma_f32_16x16x32_bf16(ahB, bh[ct], acc[1][ct], 0, 0, 0);
      acc[1][ct] = __builtin_amdgcn_mfma_f32_16x16x32_bf16(ahB, bl[ct], acc[1][ct], 0, 0, 0);
      acc[1][ct] = __builtin_amdgcn_mfma_f32_16x16x32_bf16(alB, bh[ct], acc[1][ct], 0, 0, 0);
    }
  }
#pragma unroll
  for (int rtl = 0; rtl < 2; ++rtl) {
    int rbase = n0 + rtl * 16 + (l >> 4) * 4;
    int col0 = l & 15;
#pragma unroll
    for (int ct = 0; ct < 4; ++ct) {
      int col = ct * 16 + col0;
#pragma unroll
      for (int r = 0; r < 4; ++r) {
        int node = rbase + r;
        if (node < N_NODES) h1h[(size_t)node * HIDDEN + col] = (half_t)acc[rtl][ct][r];
      }
    }
#pragma unroll
    for (int r = 0; r < 4; ++r) {
      int node = rbase + r;
      if (node < N_NODES) {
        float v = acc[rtl][4][r];
        if (col0 < 8) a_srch[(size_t)node * 8 + col0] = (half_t)v;
        else          a_dst1[(size_t)node * 8 + (col0 - 8)] = v;
      }
    }
  }
}

// ============================ layer-1 edge softmax + aggregate + layer-2 projection ============
// One wave per dst node (lane = col), barrier-free. fp16 h1 gathers, fp16 exs LDS,
// SGPR row addressing, 16-deep load-batched unroll (16 gathers in flight per wave).

__global__ __launch_bounds__(256) void k_edge1(const int* __restrict__ rowp,
                                               const int* __restrict__ ssrc,
                                               const half_t* __restrict__ a_srch,
                                               const float* __restrict__ a_dst,
                                               const half_t* __restrict__ h1h,
                                               const float* __restrict__ b1,
                                               const float* __restrict__ W2,
                                               const float* __restrict__ att_src2,
                                               const float* __restrict__ att_dst2,
                                               half_t* __restrict__ h2h,
                                               float* __restrict__ a_src2,
                                               float* __restrict__ a_dst2) {
  __shared__ __align__(16) float w2s[HIDDEN * N_CLASSES];   // 10 KB
  __shared__ float as2s[N_CLASSES], ad2s[N_CLASSES];
  __shared__ half_t exsh[4][64 * 9];                        // 4.5 KB
  __shared__ int   srcs[4][64];
  __shared__ float orow[4][64];
  int t = threadIdx.x;
  for (int i = t; i < HIDDEN * N_CLASSES; i += 256) w2s[i] = W2[i];
  if (t < N_CLASSES) { as2s[t] = att_src2[t]; ad2s[t] = att_dst2[t]; }
  __syncthreads();                       // once; all waves reach before divergence

  int wv = t >> 6, lane = t & 63;
  int node = __builtin_amdgcn_readfirstlane(blockIdx.x * 4 + wv);
  int s0 = __builtin_amdgcn_readfirstlane(rowp[node]);
  int s1 = __builtin_amdgcn_readfirstlane(rowp[node + 1]);

  float ad[8];
  {
    float4 d0 = *(const float4*)(a_dst + (size_t)node * 8);
    float4 d1 = *(const float4*)(a_dst + (size_t)node * 8 + 4);
    ad[0] = d0.x; ad[1] = d0.y; ad[2] = d0.z; ad[3] = d0.w;
    ad[4] = d1.x; ad[5] = d1.y; ad[6] = d1.z; ad[7] = d1.w;
  }
  float ac0 = 0.f, ac1 = 0.f, ac2 = 0.f, ac3 = 0.f;
  float ds0 = 0.f, ds1 = 0.f, ds2 = 0.f, ds3 = 0.f;
  int hof = lane >> 3;

  for (int base = s0; base < s1; base += 64) {
    int cn = s1 - base;
    cn = cn > 64 ? 64 : cn;
    asm volatile("" ::: "memory");       // keep prev-chunk LDS reads before new writes
    if (lane < cn) {
      int sid = ssrc[base + lane];
      h16x8 Av = *(const h16x8*)(a_srch + (size_t)sid * 8);
      srcs[wv][lane] = sid;
#pragma unroll
      for (int h = 0; h < 8; ++h) {
        float e = (float)Av[h] + ad[h];
        e = e > 0.f ? e : 0.2f * e;      // leaky_relu
        exsh[wv][lane * 9 + h] = (half_t)__expf(e);
      }
    }
    // wave-internal fence: writes visible to all lanes of this wave
    asm volatile("s_waitcnt lgkmcnt(0)" ::: "memory");
    int j = 0;
    for (; j + 16 <= cn; j += 16) {
      float ev[16]; int sj[16]; float g[16];
#pragma unroll
      for (int q = 0; q < 16; ++q) {
        ev[q] = (float)exsh[wv][(j + q) * 9 + hof];
        sj[q] = __builtin_amdgcn_readfirstlane(srcs[wv][j + q]);
      }
#pragma unroll
      for (int q = 0; q < 16; ++q)
        g[q] = (float)(h1h + (size_t)sj[q] * HIDDEN)[lane];
#pragma unroll
      for (int q = 0; q < 16; ++q) {
        if ((q & 3) == 0)      { ac0 = fmaf(ev[q], g[q], ac0); ds0 += ev[q]; }
        else if ((q & 3) == 1) { ac1 = fmaf(ev[q], g[q], ac1); ds1 += ev[q]; }
        else if ((q & 3) == 2) { ac2 = fmaf(ev[q], g[q], ac2); ds2 += ev[q]; }
        else                   { ac3 = fmaf(ev[q], g[q], ac3); ds3 += ev[q]; }
      }
    }
    for (; j + 4 <= cn; j += 4) {
      float e0 = (float)exsh[wv][j * 9 + hof];
      float e1 = (float)exsh[wv][(j + 1) * 9 + hof];
      float e2 = (float)exsh[wv][(j + 2) * 9 + hof];
      float e3 = (float)exsh[wv][(j + 3) * 9 + hof];
      int sj0 = __builtin_amdgcn_readfirstlane(srcs[wv][j]);
      int sj1 = __builtin_amdgcn_readfirstlane(srcs[wv][j + 1]);
      int sj2 = __builtin_amdgcn_readfirstlane(srcs[wv][j + 2]);
      int sj3 = __builtin_amdgcn_readfirstlane(srcs[wv][j + 3]);
      float g0 = (float)(h1h + (size_t)sj0 * HIDDEN)[lane];
      float g1 = (float)(h1h + (size_t)sj1 * HIDDEN)[lane];
      float g2 = (float)(h1h + (size_t)sj2 * HIDDEN)[lane];
      float g3 = (float)(h1h + (size_t)sj3 * HIDDEN)[lane];
      ac0 = fmaf(e0, g0, ac0);  ds0 += e0;
      ac1 = fmaf(e1, g1, ac1);  ds1 += e1;
      ac2 = fmaf(e2, g2, ac2);  ds2 += e2;
      ac3 = fmaf(e3, g3, ac3);  ds3 += e3;
    }
    for (; j < cn; ++j) {
      float e0 = (float)exsh[wv][j * 9 + hof];
      int sj0 = __builtin_amdgcn_readfirstlane(srcs[wv][j]);
      ac0 = fmaf(e0, (float)(h1h + (size_t)sj0 * HIDDEN)[lane], ac0);
      ds0 += e0;
    }
  }
  float accv = (ac0 + ac1) + (ac2 + ac3);
  float dsum = (ds0 + ds1) + (ds2 + ds3);
  float o = accv / (dsum + 1e-16f);
  o += b1[lane];
  o = o > 0.f ? o : expm1f(o);           // elu -> out1 row, kept in LDS only
  orow[wv][lane] = o;
  asm volatile("s_waitcnt lgkmcnt(0)" ::: "memory");

  // layer-2 projection: h2 = out1 @ W2, plus attention dots
  float hacc = 0.f;
  if (lane < N_CLASSES) {
#pragma unroll 16
    for (int k = 0; k < HIDDEN; ++k)
      hacc = fmaf(orow[wv][k], w2s[k * N_CLASSES + lane], hacc);
  }
  float pas = (lane < N_CLASSES) ? hacc * as2s[lane] : 0.f;
  float pad = (lane < N_CLASSES) ? hacc * ad2s[lane] : 0.f;
#pragma unroll
  for (int off = 1; off < 64; off <<= 1) {
    pas += __shfl_xor(pas, off);
    pad += __shfl_xor(pad, off);
  }
  if (lane < N_CLASSES) h2h[(size_t)node * N_CLASSES + lane] = (half_t)hacc;
  if (lane == 0) { a_src2[node] = pas; a_dst2[node] = pad; }
}

// ============================ layer-2 edge softmax + aggregate ============================

__global__ __launch_bounds__(256) void k_edge2(const int* __restrict__ rowp,
                                               const int* __restrict__ ssrc,
                                               const float* __restrict__ a_src,
                                               const float* __restrict__ a_dst,
                                               const half_t* __restrict__ h2h,
                                               const float* __restrict__ b2,
                                               float* __restrict__ out) {
  __shared__ float exs[4][64];
  __shared__ int   srcs[4][64];
  int t = threadIdx.x;
  int wv = t >> 6, lane = t & 63;
  int node = __builtin_amdgcn_readfirstlane(blockIdx.x * 4 + wv);
  int s0 = __builtin_amdgcn_readfirstlane(rowp[node]);
  int s1 = __builtin_amdgcn_readfirstlane(rowp[node + 1]);

  float adv = a_dst[node];
  float ac0 = 0.f, ac1 = 0.f, ac2 = 0.f, ac3 = 0.f;
  float ds0 = 0.f, ds1 = 0.f, ds2 = 0.f, ds3 = 0.f;
  bool act = lane < N_CLASSES;

  for (int base = s0; base < s1; base += 64) {
    int cn = s1 - base;
    cn = cn > 64 ? 64 : cn;
    asm volatile("" ::: "memory");
    if (lane < cn) {
      int sid = ssrc[base + lane];
      float e = a_src[sid] + adv;
      e = e > 0.f ? e : 0.2f * e;
      srcs[wv][lane] = sid;
      exs[wv][lane] = __expf(e);
    }
    asm volatile("s_waitcnt lgkmcnt(0)" ::: "memory");
    int j = 0;
    for (; j + 16 <= cn; j += 16) {
      float ev[16]; int sj[16]; float g[16];
#pragma unroll
      for (int q = 0; q < 16; ++q) {
        ev[q] = exs[wv][j + q];
        sj[q] = __builtin_amdgcn_readfirstlane(srcs[wv][j + q]);
      }
      if (act) {
#pragma unroll
        for (int q = 0; q < 16; ++q)
          g[q] = (float)(h2h + (size_t)sj[q] * N_CLASSES)[lane];
      }
#pragma unroll
      for (int q = 0; q < 16; ++q) {
        float gq = act ? g[q] : 0.f;
        if ((q & 3) == 0)      { ac0 = fmaf(ev[q], gq, ac0); ds0 += ev[q]; }
        else if ((q & 3) == 1) { ac1 = fmaf(ev[q], gq, ac1); ds1 += ev[q]; }
        else if ((q & 3) == 2) { ac2 = fmaf(ev[q], gq, ac2); ds2 += ev[q]; }
        else                   { ac3 = fmaf(ev[q], gq, ac3); ds3 += ev[q]; }
      }
    }
    for (; j < cn; ++j) {
      float e0 = exs[wv][j];
      int sj0 = __builtin_amdgcn_readfirstlane(srcs[wv][j]);
      ds0 += e0;
      if (act) ac0 = fmaf(e0, (float)(h2h + (size_t)sj0 * N_CLASSES)[lane], ac0);
    }
  }
  float accv = (ac0 + ac1) + (ac2 + ac3);
  float dsum = (ds0 + ds1) + (ds2 + ds3);
  if (act)
    out[(size_t)node * N_CLASSES + lane] = accv / (dsum + 1e-16f) + b2[lane];
}

// ============================ launch ============================

extern "C" void kernel_launch(void* const* d_in, const int* in_sizes, int n_in,
                              void* d_out, int out_size, void* d_ws, size_t ws_size,
                              hipStream_t stream) {
  const float* x        = (const float*)d_in[0];
  const int*   ei       = (const int*)d_in[1];
  const float* W1       = (const float*)d_in[2];
  const float* att_src1 = (const float*)d_in[3];
  const float* att_dst1 = (const float*)d_in[4];
  const float* b1       = (const float*)d_in[5];
  const float* W2       = (const float*)d_in[6];
  const float* att_src2 = (const float*)d_in[7];
  const float* att_dst2 = (const float*)d_in[8];
  const float* b2       = (const float*)d_in[9];
  float* out = (float*)d_out;

  char* w = (char*)d_ws;
  half_t* h1h    = (half_t*)(w);                  // 12.8 MB
  half_t* h2h    = (half_t*)(w + 12800000);       //  8.0 MB (stride 40)
  half_t* a_srch = (half_t*)(w + 20800000);       //  1.6 MB
  float* a_dst1  = (float*)(w + 22400000);        //  3.2 MB
  int*   rowp    = (int*)(w + 25600000);          //  400 KB
  int*   ssrc    = (int*)(w + 26000128);          //  6.8 MB
  short* w1fh    = (short*)(w + 32800128);        //   80 KB (512 x 80)
  short* w1fl    = (short*)(w + 32882048);        //   80 KB
  float* a_src2  = (float*)(w + 32964096);        //  400 KB
  float* a_dst2  = (float*)(w + 33364096);        //  400 KB
  int*   btot    = (int*)(w + 33764096);          //  784 B
  int*   bbase   = (int*)(w + 33765120);          //  788 B
  // build-time aliases (dead before their region's writer runs):
  unsigned* ebuf = (unsigned*)(w);                //  6.8 MB, aliases h1h
  int*   ghT     = (int*)(w + 12800000);          //  401 KB, aliases h2h

  // --- W1 fragment precompute + CSR build ---
  k_wprep<<<(N_FEAT * HIDDEN + N_FEAT * 16 + 255) / 256, 256, 0, stream>>>(
      W1, att_src1, att_dst1, w1fh, w1fl);
  k_bhist<<<SC_NBLK, 256, 0, stream>>>(ei, ghT);
  k_scan1<<<NBUCK, 256, 0, stream>>>(ghT, btot);
  k_scan2<<<1, 256, 0, stream>>>(btot, bbase);
  k_bscatter<<<SC_NBLK, 256, 0, stream>>>(ei, ghT, bbase, ebuf);
  k_fine<<<NBUCK, 256, 0, stream>>>(ebuf, bbase, rowp, ssrc);

  // --- layer 1 (+ fused attention coeffs + fused layer-2 projection) ---
  k_gemm1<<<(N_NODES + 127) / 128, 256, 0, stream>>>(x, w1fh, w1fl, h1h, a_srch, a_dst1);
  k_edge1<<<N_NODES / 4, 256, 0, stream>>>(rowp, ssrc, a_srch, a_dst1, h1h, b1,
                                           W2, att_src2, att_dst2, h2h, a_src2, a_dst2);

  // --- layer 2 ---
  k_edge2<<<N_NODES / 4, 256, 0, stream>>>(rowp, ssrc, a_src2, a_dst2, h2h, b2, out);
}

// Round 18
// 280.315 us; speedup vs baseline: 1.0859x; 1.0859x over previous
//
#include <hip/hip_runtime.h>
#include <math.h>

#define N_NODES   100000
#define N_EDGES   1600000
#define E_TOT     (N_EDGES + N_NODES)
#define N_FEAT    512
#define HEADS     8
#define F_HEAD    8
#define HIDDEN    64
#define N_CLASSES 40

#define BSHIFT    9
#define NBUCK     196                      // ceil(N_NODES / 512)
#define SC_NBLK   512
#define SC_CHUNK  ((E_TOT + SC_NBLK - 1) / SC_NBLK)   // 3321

#define CT        5                        // B ct-tiles: 4 (W1) + 1 (Wsrc|Wdst)

typedef __attribute__((ext_vector_type(8))) short short8_t;
typedef __attribute__((ext_vector_type(4))) float f32x4;
typedef _Float16 half_t;
typedef __attribute__((ext_vector_type(8))) _Float16 h16x8;

// split fp32 -> bf16 hi + bf16 lo (both RNE)
__device__ inline void f2bf2(float x, unsigned short& h, unsigned short& l) {
  union { float f; unsigned u; } a; a.f = x;
  unsigned rh = a.u + 0x7FFFu + ((a.u >> 16) & 1u);
  unsigned short hv = (unsigned short)(rh >> 16);
  union { unsigned u; float f; } hf; hf.u = ((unsigned)hv) << 16;
  union { float f; unsigned u; } b; b.f = x - hf.f;
  unsigned rl = b.u + 0x7FFFu + ((b.u >> 16) & 1u);
  h = hv;
  l = (unsigned short)(rl >> 16);
}

__device__ inline void cvt8(const float4& v0, const float4& v1, short8_t& hi, short8_t& lo) {
  float v[8] = {v0.x, v0.y, v0.z, v0.w, v1.x, v1.y, v1.z, v1.w};
#pragma unroll
  for (int e = 0; e < 8; ++e) {
    unsigned short hh, ll;
    f2bf2(v[e], hh, ll);
    hi[e] = (short)hh;
    lo[e] = (short)ll;
  }
}

// ============================ CSR build: two-level counting sort ============================

__global__ __launch_bounds__(256) void k_bhist(const int* __restrict__ ei,
                                               int* __restrict__ ghT) {
  __shared__ int h[NBUCK];
  int b = blockIdx.x, t = threadIdx.x;
  for (int i = t; i < NBUCK; i += 256) h[i] = 0;
  __syncthreads();
  int e0 = b * SC_CHUNK;
  int e1 = e0 + SC_CHUNK; if (e1 > E_TOT) e1 = E_TOT;
  for (int e = e0 + t; e < e1; e += 256) {
    int dst = (e < N_EDGES) ? ei[N_EDGES + e] : (e - N_EDGES);
    atomicAdd(&h[dst >> BSHIFT], 1);
  }
  __syncthreads();
  for (int i = t; i < NBUCK; i += 256) ghT[i * SC_NBLK + b] = h[i];
}

// per-bucket: exclusive prefix over 512 blocks (2 elems/thread) + bucket total
__global__ __launch_bounds__(256) void k_scan1(int* __restrict__ ghT,
                                               int* __restrict__ btot) {
  __shared__ int red[256];
  int k = blockIdx.x, t = threadIdx.x;
  int a = ghT[k * SC_NBLK + 2 * t];
  int b = ghT[k * SC_NBLK + 2 * t + 1];
  int s = a + b;
  red[t] = s;
  __syncthreads();
  for (int off = 1; off < 256; off <<= 1) {
    int add = (t >= off) ? red[t - off] : 0;
    __syncthreads();
    red[t] += add;
    __syncthreads();
  }
  int excl = red[t] - s;
  ghT[k * SC_NBLK + 2 * t]     = excl;
  ghT[k * SC_NBLK + 2 * t + 1] = excl + a;
  if (t == 255) btot[k] = red[255];
}

__global__ __launch_bounds__(256) void k_scan2(const int* __restrict__ btot,
                                               int* __restrict__ bbase) {
  __shared__ int red[256];
  int t = threadIdx.x;
  int v = (t < NBUCK) ? btot[t] : 0;
  red[t] = v;
  __syncthreads();
  for (int off = 1; off < 256; off <<= 1) {
    int add = (t >= off) ? red[t - off] : 0;
    __syncthreads();
    red[t] += add;
    __syncthreads();
  }
  if (t < NBUCK) bbase[t] = red[t] - v;
  if (t == NBUCK - 1) bbase[NBUCK] = red[t];
}

__global__ __launch_bounds__(256) void k_bscatter(const int* __restrict__ ei,
                                                  const int* __restrict__ ghT,
                                                  const int* __restrict__ bbase,
                                                  unsigned* __restrict__ ebuf) {
  __shared__ int offs[256];
  __shared__ int cnt[256];
  int b = blockIdx.x, t = threadIdx.x;
  offs[t] = (t < NBUCK) ? (ghT[t * SC_NBLK + b] + bbase[t]) : 0;
  cnt[t] = 0;
  __syncthreads();
  int e0 = b * SC_CHUNK;
  int e1 = e0 + SC_CHUNK; if (e1 > E_TOT) e1 = E_TOT;
  for (int e = e0 + t; e < e1; e += 256) {
    int src, dst;
    if (e < N_EDGES) { src = ei[e]; dst = ei[N_EDGES + e]; }
    else             { src = e - N_EDGES; dst = src; }
    int k = dst >> BSHIFT;
    int r = atomicAdd(&cnt[k], 1);
    ebuf[offs[k] + r] = (unsigned)src | ((unsigned)(dst & 511) << 17);
  }
}

__global__ __launch_bounds__(256) void k_fine(const unsigned* __restrict__ ebuf,
                                              const int* __restrict__ bbase,
                                              int* __restrict__ rowp,
                                              int* __restrict__ ssrc) {
  __shared__ int cnt[512];
  __shared__ int red[256];
  __shared__ int cur[512];
  int k = blockIdx.x, t = threadIdx.x;
  int base = bbase[k], end = bbase[k + 1];
  cnt[t] = 0; cnt[t + 256] = 0;
  __syncthreads();
  for (int i = base + t; i < end; i += 256) atomicAdd(&cnt[ebuf[i] >> 17], 1);
  __syncthreads();
  int c0 = cnt[2 * t], c1 = cnt[2 * t + 1];
  int s = c0 + c1;
  red[t] = s;
  __syncthreads();
  for (int off = 1; off < 256; off <<= 1) {
    int add = (t >= off) ? red[t - off] : 0;
    __syncthreads();
    red[t] += add;
    __syncthreads();
  }
  int excl = red[t] - s;
  int p0 = base + excl;
  int p1 = p0 + c0;
  cur[2 * t] = p0; cur[2 * t + 1] = p1;
  int node = (k << BSHIFT) + 2 * t;
  if (node < N_NODES)     rowp[node]     = p0;
  if (node + 1 < N_NODES) rowp[node + 1] = p1;
  if (k == NBUCK - 1 && t == 0) rowp[N_NODES] = E_TOT;
  __syncthreads();
  for (int i = base + t; i < end; i += 256) {
    unsigned p = ebuf[i];
    int pos = atomicAdd(&cur[p >> 17], 1);
    ssrc[pos] = (int)(p & 0x1FFFFu);
  }
}

// ============================ W1/Wsrc/Wdst -> fragment-ordered bf16 hi/lo (fused) ============

__global__ void k_wprep(const float* __restrict__ W1, const float* __restrict__ att_src1,
                        const float* __restrict__ att_dst1, short* __restrict__ w1fh,
                        short* __restrict__ w1fl) {
  int idx = blockIdx.x * blockDim.x + threadIdx.x;
  if (idx < N_FEAT * HIDDEN) {
    int e    = idx & 7;
    int lane = (idx >> 3) & 63;
    int ct   = (idx >> 9) & 3;
    int ks   = idx >> 11;
    int col = ct * 16 + (lane & 15);
    int k   = ks * 32 + (lane >> 4) * 8 + e;
    unsigned short h, l;
    f2bf2(W1[k * HIDDEN + col], h, l);
    int didx = ((ks * CT + ct) * 64 + lane) * 8 + e;
    w1fh[didx] = (short)h;
    w1fl[didx] = (short)l;
  } else if (idx < N_FEAT * HIDDEN + N_FEAT * 16) {
    int i2 = idx - N_FEAT * HIDDEN;
    int c = i2 & 15;
    int k = i2 >> 4;
    int cc = c & 7;
    const float* att = (c < 8) ? att_src1 : att_dst1;
    float v = 0.f;
#pragma unroll
    for (int f = 0; f < 8; ++f) v = fmaf(W1[k * HIDDEN + cc * 8 + f], att[cc * 8 + f], v);
    unsigned short h, l;
    f2bf2(v, h, l);
    int lane = ((k >> 3) & 3) * 16 + c;
    int ks = k >> 5, e = k & 7;
    int didx = ((ks * CT + 4) * 64 + lane) * 8 + e;
    w1fh[didx] = (short)h;
    w1fl[didx] = (short)l;
  }
}

// ============================ Layer 1 GEMM: [h1 | a_src1 | a_dst1] = x @ [W1|Wsrc|Wdst] ============

__global__ __launch_bounds__(256) void k_gemm1(const float* __restrict__ x,
                                               const short* __restrict__ w1fh,
                                               const short* __restrict__ w1fl,
                                               half_t* __restrict__ h1h,
                                               half_t* __restrict__ a_srch,
                                               float* __restrict__ a_dst1) {
  int t = threadIdx.x;
  int w = t >> 6, l = t & 63;
  int n0 = blockIdx.x * 128 + w * 32;
  int r0 = l & 15;
  int kq8 = (l >> 4) * 8;
  const float* pA = x + (size_t)(n0 + r0) * N_FEAT + kq8;
  const float* pB = x + (size_t)(n0 + 16 + r0) * N_FEAT + kq8;
  bool vA = (n0 + r0) < N_NODES;
  bool vB = (n0 + 16 + r0) < N_NODES;

  f32x4 acc[2][CT];
#pragma unroll
  for (int i = 0; i < 2; ++i)
#pragma unroll
    for (int j = 0; j < CT; ++j) acc[i][j] = (f32x4){0.f, 0.f, 0.f, 0.f};

#pragma unroll 2
  for (int gks = 0; gks < 16; ++gks) {
    int boff = gks * (CT * 512) + l * 8;
    short8_t bh[CT], bl[CT];
#pragma unroll
    for (int ct = 0; ct < CT; ++ct) {
      bh[ct] = *(const short8_t*)(w1fh + boff + ct * 512);
      bl[ct] = *(const short8_t*)(w1fl + boff + ct * 512);
    }
    float4 a0 = make_float4(0.f, 0.f, 0.f, 0.f), a1 = a0, c0 = a0, c1 = a0;
    if (vA) {
      const float4* p = (const float4*)(pA + gks * 32);
      a0 = p[0]; a1 = p[1];
    }
    if (vB) {
      const float4* p = (const float4*)(pB + gks * 32);
      c0 = p[0]; c1 = p[1];
    }
    short8_t ahA, alA, ahB, alB;
    cvt8(a0, a1, ahA, alA);
    cvt8(c0, c1, ahB, alB);
#pragma unroll
    for (int ct = 0; ct < CT; ++ct) {
      acc[0][ct] = __builtin_amdgcn_mfma_f32_16x16x32_bf16(ahA, bh[ct], acc[0][ct], 0, 0, 0);
      acc[0][ct] = __builtin_amdgcn_mfma_f32_16x16x32_bf16(ahA, bl[ct], acc[0][ct], 0, 0, 0);
      acc[0][ct] = __builtin_amdgcn_mfma_f32_16x16x32_bf16(alA, bh[ct], acc[0][ct], 0, 0, 0);
      acc[1][ct] = __builtin_amdgcn_mfma_f32_16x16x32_bf16(ahB, bh[ct], acc[1][ct], 0, 0, 0);
      acc[1][ct] = __builtin_amdgcn_mfma_f32_16x16x32_bf16(ahB, bl[ct], acc[1][ct], 0, 0, 0);
      acc[1][ct] = __builtin_amdgcn_mfma_f32_16x16x32_bf16(alB, bh[ct], acc[1][ct], 0, 0, 0);
    }
  }
#pragma unroll
  for (int rtl = 0; rtl < 2; ++rtl) {
    int rbase = n0 + rtl * 16 + (l >> 4) * 4;
    int col0 = l & 15;
#pragma unroll
    for (int ct = 0; ct < 4; ++ct) {
      int col = ct * 16 + col0;
#pragma unroll
      for (int r = 0; r < 4; ++r) {
        int node = rbase + r;
        if (node < N_NODES) h1h[(size_t)node * HIDDEN + col] = (half_t)acc[rtl][ct][r];
      }
    }
#pragma unroll
    for (int r = 0; r < 4; ++r) {
      int node = rbase + r;
      if (node < N_NODES) {
        float v = acc[rtl][4][r];
        if (col0 < 8) a_srch[(size_t)node * 8 + col0] = (half_t)v;
        else          a_dst1[(size_t)node * 8 + (col0 - 8)] = v;
      }
    }
  }
}

// ============================ layer-1 edge softmax + aggregate + layer-2 projection ============
// One wave per dst node (lane = col), barrier-free. fp16 h1 gathers, fp16 exs LDS
// (17.2 KB -> 8 blocks/CU), SGPR row addressing, 8-deep unroll.

__global__ __launch_bounds__(256) void k_edge1(const int* __restrict__ rowp,
                                               const int* __restrict__ ssrc,
                                               const half_t* __restrict__ a_srch,
                                               const float* __restrict__ a_dst,
                                               const half_t* __restrict__ h1h,
                                               const float* __restrict__ b1,
                                               const float* __restrict__ W2,
                                               const float* __restrict__ att_src2,
                                               const float* __restrict__ att_dst2,
                                               half_t* __restrict__ h2h,
                                               float* __restrict__ a_src2,
                                               float* __restrict__ a_dst2) {
  __shared__ __align__(16) float w2s[HIDDEN * N_CLASSES];   // 10 KB
  __shared__ float as2s[N_CLASSES], ad2s[N_CLASSES];
  __shared__ half_t exsh[4][64 * 9];                        // 4.5 KB
  __shared__ int   srcs[4][64];
  __shared__ float orow[4][64];
  int t = threadIdx.x;
  for (int i = t; i < HIDDEN * N_CLASSES; i += 256) w2s[i] = W2[i];
  if (t < N_CLASSES) { as2s[t] = att_src2[t]; ad2s[t] = att_dst2[t]; }
  __syncthreads();                       // once; all waves reach before divergence

  int wv = t >> 6, lane = t & 63;
  int node = __builtin_amdgcn_readfirstlane(blockIdx.x * 4 + wv);
  int s0 = __builtin_amdgcn_readfirstlane(rowp[node]);
  int s1 = __builtin_amdgcn_readfirstlane(rowp[node + 1]);

  float ad[8];
  {
    float4 d0 = *(const float4*)(a_dst + (size_t)node * 8);
    float4 d1 = *(const float4*)(a_dst + (size_t)node * 8 + 4);
    ad[0] = d0.x; ad[1] = d0.y; ad[2] = d0.z; ad[3] = d0.w;
    ad[4] = d1.x; ad[5] = d1.y; ad[6] = d1.z; ad[7] = d1.w;
  }
  float ac0 = 0.f, ac1 = 0.f, ac2 = 0.f, ac3 = 0.f;
  float ds0 = 0.f, ds1 = 0.f, ds2 = 0.f, ds3 = 0.f;
  int hof = lane >> 3;

  for (int base = s0; base < s1; base += 64) {
    int cn = s1 - base;
    cn = cn > 64 ? 64 : cn;
    asm volatile("" ::: "memory");       // keep prev-chunk LDS reads before new writes
    if (lane < cn) {
      int sid = ssrc[base + lane];
      h16x8 Av = *(const h16x8*)(a_srch + (size_t)sid * 8);
      srcs[wv][lane] = sid;
#pragma unroll
      for (int h = 0; h < 8; ++h) {
        float e = (float)Av[h] + ad[h];
        e = e > 0.f ? e : 0.2f * e;      // leaky_relu
        exsh[wv][lane * 9 + h] = (half_t)__expf(e);
      }
    }
    // wave-internal fence: writes visible to all lanes of this wave
    asm volatile("s_waitcnt lgkmcnt(0)" ::: "memory");
    int j = 0;
    for (; j + 8 <= cn; j += 8) {
      float e0 = (float)exsh[wv][j * 9 + hof];
      float e1 = (float)exsh[wv][(j + 1) * 9 + hof];
      float e2 = (float)exsh[wv][(j + 2) * 9 + hof];
      float e3 = (float)exsh[wv][(j + 3) * 9 + hof];
      float e4 = (float)exsh[wv][(j + 4) * 9 + hof];
      float e5 = (float)exsh[wv][(j + 5) * 9 + hof];
      float e6 = (float)exsh[wv][(j + 6) * 9 + hof];
      float e7 = (float)exsh[wv][(j + 7) * 9 + hof];
      int sj0 = __builtin_amdgcn_readfirstlane(srcs[wv][j]);
      int sj1 = __builtin_amdgcn_readfirstlane(srcs[wv][j + 1]);
      int sj2 = __builtin_amdgcn_readfirstlane(srcs[wv][j + 2]);
      int sj3 = __builtin_amdgcn_readfirstlane(srcs[wv][j + 3]);
      int sj4 = __builtin_amdgcn_readfirstlane(srcs[wv][j + 4]);
      int sj5 = __builtin_amdgcn_readfirstlane(srcs[wv][j + 5]);
      int sj6 = __builtin_amdgcn_readfirstlane(srcs[wv][j + 6]);
      int sj7 = __builtin_amdgcn_readfirstlane(srcs[wv][j + 7]);
      float g0 = (float)(h1h + (size_t)sj0 * HIDDEN)[lane];
      float g1 = (float)(h1h + (size_t)sj1 * HIDDEN)[lane];
      float g2 = (float)(h1h + (size_t)sj2 * HIDDEN)[lane];
      float g3 = (float)(h1h + (size_t)sj3 * HIDDEN)[lane];
      float g4 = (float)(h1h + (size_t)sj4 * HIDDEN)[lane];
      float g5 = (float)(h1h + (size_t)sj5 * HIDDEN)[lane];
      float g6 = (float)(h1h + (size_t)sj6 * HIDDEN)[lane];
      float g7 = (float)(h1h + (size_t)sj7 * HIDDEN)[lane];
      ac0 = fmaf(e0, g0, ac0);  ds0 += e0;
      ac1 = fmaf(e1, g1, ac1);  ds1 += e1;
      ac2 = fmaf(e2, g2, ac2);  ds2 += e2;
      ac3 = fmaf(e3, g3, ac3);  ds3 += e3;
      ac0 = fmaf(e4, g4, ac0);  ds0 += e4;
      ac1 = fmaf(e5, g5, ac1);  ds1 += e5;
      ac2 = fmaf(e6, g6, ac2);  ds2 += e6;
      ac3 = fmaf(e7, g7, ac3);  ds3 += e7;
    }
    for (; j + 4 <= cn; j += 4) {
      float e0 = (float)exsh[wv][j * 9 + hof];
      float e1 = (float)exsh[wv][(j + 1) * 9 + hof];
      float e2 = (float)exsh[wv][(j + 2) * 9 + hof];
      float e3 = (float)exsh[wv][(j + 3) * 9 + hof];
      int sj0 = __builtin_amdgcn_readfirstlane(srcs[wv][j]);
      int sj1 = __builtin_amdgcn_readfirstlane(srcs[wv][j + 1]);
      int sj2 = __builtin_amdgcn_readfirstlane(srcs[wv][j + 2]);
      int sj3 = __builtin_amdgcn_readfirstlane(srcs[wv][j + 3]);
      float g0 = (float)(h1h + (size_t)sj0 * HIDDEN)[lane];
      float g1 = (float)(h1h + (size_t)sj1 * HIDDEN)[lane];
      float g2 = (float)(h1h + (size_t)sj2 * HIDDEN)[lane];
      float g3 = (float)(h1h + (size_t)sj3 * HIDDEN)[lane];
      ac0 = fmaf(e0, g0, ac0);  ds0 += e0;
      ac1 = fmaf(e1, g1, ac1);  ds1 += e1;
      ac2 = fmaf(e2, g2, ac2);  ds2 += e2;
      ac3 = fmaf(e3, g3, ac3);  ds3 += e3;
    }
    for (; j < cn; ++j) {
      float e0 = (float)exsh[wv][j * 9 + hof];
      int sj0 = __builtin_amdgcn_readfirstlane(srcs[wv][j]);
      ac0 = fmaf(e0, (float)(h1h + (size_t)sj0 * HIDDEN)[lane], ac0);
      ds0 += e0;
    }
  }
  float accv = (ac0 + ac1) + (ac2 + ac3);
  float dsum = (ds0 + ds1) + (ds2 + ds3);
  float o = accv / (dsum + 1e-16f);
  o += b1[lane];
  o = o > 0.f ? o : expm1f(o);           // elu -> out1 row, kept in LDS only
  orow[wv][lane] = o;
  asm volatile("s_waitcnt lgkmcnt(0)" ::: "memory");

  // layer-2 projection: h2 = out1 @ W2, plus attention dots
  float hacc = 0.f;
  if (lane < N_CLASSES) {
#pragma unroll 16
    for (int k = 0; k < HIDDEN; ++k)
      hacc = fmaf(orow[wv][k], w2s[k * N_CLASSES + lane], hacc);
  }
  float pas = (lane < N_CLASSES) ? hacc * as2s[lane] : 0.f;
  float pad = (lane < N_CLASSES) ? hacc * ad2s[lane] : 0.f;
#pragma unroll
  for (int off = 1; off < 64; off <<= 1) {
    pas += __shfl_xor(pas, off);
    pad += __shfl_xor(pad, off);
  }
  if (lane < N_CLASSES) h2h[(size_t)node * N_CLASSES + lane] = (half_t)hacc;
  if (lane == 0) { a_src2[node] = pas; a_dst2[node] = pad; }
}

// ============================ layer-2 edge softmax + aggregate ============================

__global__ __launch_bounds__(256) void k_edge2(const int* __restrict__ rowp,
                                               const int* __restrict__ ssrc,
                                               const float* __restrict__ a_src,
                                               const float* __restrict__ a_dst,
                                               const half_t* __restrict__ h2h,
                                               const float* __restrict__ b2,
                                               float* __restrict__ out) {
  __shared__ float exs[4][64];
  __shared__ int   srcs[4][64];
  int t = threadIdx.x;
  int wv = t >> 6, lane = t & 63;
  int node = __builtin_amdgcn_readfirstlane(blockIdx.x * 4 + wv);
  int s0 = __builtin_amdgcn_readfirstlane(rowp[node]);
  int s1 = __builtin_amdgcn_readfirstlane(rowp[node + 1]);

  float adv = a_dst[node];
  float ac0 = 0.f, ac1 = 0.f, ac2 = 0.f, ac3 = 0.f;
  float ds0 = 0.f, ds1 = 0.f, ds2 = 0.f, ds3 = 0.f;
  bool act = lane < N_CLASSES;

  for (int base = s0; base < s1; base += 64) {
    int cn = s1 - base;
    cn = cn > 64 ? 64 : cn;
    asm volatile("" ::: "memory");
    if (lane < cn) {
      int sid = ssrc[base + lane];
      float e = a_src[sid] + adv;
      e = e > 0.f ? e : 0.2f * e;
      srcs[wv][lane] = sid;
      exs[wv][lane] = __expf(e);
    }
    asm volatile("s_waitcnt lgkmcnt(0)" ::: "memory");
    int j = 0;
    for (; j + 8 <= cn; j += 8) {
      float e0 = exs[wv][j],     e1 = exs[wv][j + 1];
      float e2 = exs[wv][j + 2], e3 = exs[wv][j + 3];
      float e4 = exs[wv][j + 4], e5 = exs[wv][j + 5];
      float e6 = exs[wv][j + 6], e7 = exs[wv][j + 7];
      int sj0 = __builtin_amdgcn_readfirstlane(srcs[wv][j]);
      int sj1 = __builtin_amdgcn_readfirstlane(srcs[wv][j + 1]);
      int sj2 = __builtin_amdgcn_readfirstlane(srcs[wv][j + 2]);
      int sj3 = __builtin_amdgcn_readfirstlane(srcs[wv][j + 3]);
      int sj4 = __builtin_amdgcn_readfirstlane(srcs[wv][j + 4]);
      int sj5 = __builtin_amdgcn_readfirstlane(srcs[wv][j + 5]);
      int sj6 = __builtin_amdgcn_readfirstlane(srcs[wv][j + 6]);
      int sj7 = __builtin_amdgcn_readfirstlane(srcs[wv][j + 7]);
      ds0 += e0; ds1 += e1; ds2 += e2; ds3 += e3;
      ds0 += e4; ds1 += e5; ds2 += e6; ds3 += e7;
      if (act) {
        float g0 = (float)(h2h + (size_t)sj0 * N_CLASSES)[lane];
        float g1 = (float)(h2h + (size_t)sj1 * N_CLASSES)[lane];
        float g2 = (float)(h2h + (size_t)sj2 * N_CLASSES)[lane];
        float g3 = (float)(h2h + (size_t)sj3 * N_CLASSES)[lane];
        float g4 = (float)(h2h + (size_t)sj4 * N_CLASSES)[lane];
        float g5 = (float)(h2h + (size_t)sj5 * N_CLASSES)[lane];
        float g6 = (float)(h2h + (size_t)sj6 * N_CLASSES)[lane];
        float g7 = (float)(h2h + (size_t)sj7 * N_CLASSES)[lane];
        ac0 = fmaf(e0, g0, ac0); ac1 = fmaf(e1, g1, ac1);
        ac2 = fmaf(e2, g2, ac2); ac3 = fmaf(e3, g3, ac3);
        ac0 = fmaf(e4, g4, ac0); ac1 = fmaf(e5, g5, ac1);
        ac2 = fmaf(e6, g6, ac2); ac3 = fmaf(e7, g7, ac3);
      }
    }
    for (; j < cn; ++j) {
      float e0 = exs[wv][j];
      int sj0 = __builtin_amdgcn_readfirstlane(srcs[wv][j]);
      ds0 += e0;
      if (act) ac0 = fmaf(e0, (float)(h2h + (size_t)sj0 * N_CLASSES)[lane], ac0);
    }
  }
  float accv = (ac0 + ac1) + (ac2 + ac3);
  float dsum = (ds0 + ds1) + (ds2 + ds3);
  if (act)
    out[(size_t)node * N_CLASSES + lane] = accv / (dsum + 1e-16f) + b2[lane];
}

// ============================ launch ============================

extern "C" void kernel_launch(void* const* d_in, const int* in_sizes, int n_in,
                              void* d_out, int out_size, void* d_ws, size_t ws_size,
                              hipStream_t stream) {
  const float* x        = (const float*)d_in[0];
  const int*   ei       = (const int*)d_in[1];
  const float* W1       = (const float*)d_in[2];
  const float* att_src1 = (const float*)d_in[3];
  const float* att_dst1 = (const float*)d_in[4];
  const float* b1       = (const float*)d_in[5];
  const float* W2       = (const float*)d_in[6];
  const float* att_src2 = (const float*)d_in[7];
  const float* att_dst2 = (const float*)d_in[8];
  const float* b2       = (const float*)d_in[9];
  float* out = (float*)d_out;

  char* w = (char*)d_ws;
  half_t* h1h    = (half_t*)(w);                  // 12.8 MB
  half_t* h2h    = (half_t*)(w + 12800000);       //  8.0 MB (stride 40)
  half_t* a_srch = (half_t*)(w + 20800000);       //  1.6 MB
  float* a_dst1  = (float*)(w + 22400000);        //  3.2 MB
  int*   rowp    = (int*)(w + 25600000);          //  400 KB
  int*   ssrc    = (int*)(w + 26000128);          //  6.8 MB
  short* w1fh    = (short*)(w + 32800128);        //   80 KB (512 x 80)
  short* w1fl    = (short*)(w + 32882048);        //   80 KB
  float* a_src2  = (float*)(w + 32964096);        //  400 KB
  float* a_dst2  = (float*)(w + 33364096);        //  400 KB
  int*   btot    = (int*)(w + 33764096);          //  784 B
  int*   bbase   = (int*)(w + 33765120);          //  788 B
  // build-time aliases (dead before their region's writer runs):
  unsigned* ebuf = (unsigned*)(w);                //  6.8 MB, aliases h1h
  int*   ghT     = (int*)(w + 12800000);          //  401 KB, aliases h2h

  // --- W1 fragment precompute + CSR build ---
  k_wprep<<<(N_FEAT * HIDDEN + N_FEAT * 16 + 255) / 256, 256, 0, stream>>>(
      W1, att_src1, att_dst1, w1fh, w1fl);
  k_bhist<<<SC_NBLK, 256, 0, stream>>>(ei, ghT);
  k_scan1<<<NBUCK, 256, 0, stream>>>(ghT, btot);
  k_scan2<<<1, 256, 0, stream>>>(btot, bbase);
  k_bscatter<<<SC_NBLK, 256, 0, stream>>>(ei, ghT, bbase, ebuf);
  k_fine<<<NBUCK, 256, 0, stream>>>(ebuf, bbase, rowp, ssrc);

  // --- layer 1 (+ fused attention coeffs + fused layer-2 projection) ---
  k_gemm1<<<(N_NODES + 127) / 128, 256, 0, stream>>>(x, w1fh, w1fl, h1h, a_srch, a_dst1);
  k_edge1<<<N_NODES / 4, 256, 0, stream>>>(rowp, ssrc, a_srch, a_dst1, h1h, b1,
                                           W2, att_src2, att_dst2, h2h, a_src2, a_dst2);

  // --- layer 2 ---
  k_edge2<<<N_NODES / 4, 256, 0, stream>>>(rowp, ssrc, a_src2, a_dst2, h2h, b2, out);
}